// Round 1
// 166.887 us; speedup vs baseline: 1.0703x; 1.0703x over previous
//
#include <hip/hip_runtime.h>
#include <stdint.h>

// Problem: out[m][n] = sum_k x[m][k] * w[n][k] + bias[n]
//   M=256, N=16384, K=4096, w = dequant(2-bit, group=16 along k)
// This version: BM=256 (dequant each group ONCE), BN=64, BK=64, 512 thr.
// A is consumed directly from the fragment-ordered workspace (no LDS for A);
// only B goes through LDS (16KB double-buffered). 8 waves = 4 (m) x 2 (k-half),
// k-split partials merged through LDS scratch in the epilogue.
#define M_DIM 256
#define N_DIM 16384
#define K_DIM 4096
#define BN 64
#define BK 64
#define NT (K_DIM / BK)   // 64 k-tiles

typedef __bf16 bf16x8 __attribute__((ext_vector_type(8)));
typedef float  f32x4  __attribute__((ext_vector_type(4)));

// fp32 -> bf16 bits, round-nearest-even (finite inputs)
__device__ __forceinline__ uint32_t f2bf(float f) {
  uint32_t u = __float_as_uint(f);
  return (u + 0x7fffu + ((u >> 16) & 1u)) >> 16;
}

// ---------------------------------------------------------------------------
// Kernel 1 (unchanged): x fp32 [256][4096] -> bf16 fragment-chunk order.
// Chunk = (m-block of 16 rows) x (k-chunk of 32): 64 slots x 16B.
// Slot L holds row (L&15), k = (L>>4)*8 .. +7  (MFMA 16x16x32 A-frag order).
// ws uint4 index = (mb_glob*128 + kch)*64 + L.
// ---------------------------------------------------------------------------
__global__ __launch_bounds__(256) void cvt_x_kernel(const float* __restrict__ x,
                                                    uint4* __restrict__ ws) {
  int T = blockIdx.x * 256 + threadIdx.x;       // 0..131071
  int mb_glob = T >> 13;                        // 16 m-blocks
  int r       = T & 8191;
  int kch     = r >> 6;                         // 128 k-chunks
  int L       = r & 63;
  int row = mb_glob * 16 + (L & 15);
  int k   = kch * 32 + (L >> 4) * 8;
  const float* p = x + (size_t)row * K_DIM + k;
  float4 a = *(const float4*)p;
  float4 b = *(const float4*)(p + 4);
  uint4 o;
  o.x = f2bf(a.x) | (f2bf(a.y) << 16);
  o.y = f2bf(a.z) | (f2bf(a.w) << 16);
  o.z = f2bf(b.x) | (f2bf(b.y) << 16);
  o.w = f2bf(b.z) | (f2bf(b.w) << 16);
  ws[T] = o;
}

// ---------------------------------------------------------------------------
// Dequant 8 elems (2 packed q2 words; 4 crumbs in each low byte) of one group.
// Table entries {-n, a-n, 2a-n, 3a-n}, a = n*2/3 -- bit-identical to the
// previous per-element fmaf+f2bf path.  v_perm_b32 picks the bf16 entry per
// crumb: sel = (t0|(t1<<16))*0x0202 + 0x01000100 selects byte pairs (2t,2t+1)
// from {thi:tlo}.
// ---------------------------------------------------------------------------
__device__ __forceinline__ uint4 deq8(uint2 q, float nv) {
  float a2 = nv * (2.0f / 3.0f);
  uint32_t tlo = f2bf(-nv) | (f2bf(fmaf(1.0f, a2, -nv)) << 16);
  uint32_t thi = f2bf(fmaf(2.0f, a2, -nv)) | (f2bf(fmaf(3.0f, a2, -nv)) << 16);
  uint32_t s0 = ((q.x & 3u) | ((q.x & 0xCu) << 14)) * 0x0202u + 0x01000100u;
  uint32_t s1 = (((q.x >> 4) & 3u) | ((q.x & 0xC0u) << 10)) * 0x0202u + 0x01000100u;
  uint32_t s2 = ((q.y & 3u) | ((q.y & 0xCu) << 14)) * 0x0202u + 0x01000100u;
  uint32_t s3 = (((q.y >> 4) & 3u) | ((q.y & 0xC0u) << 10)) * 0x0202u + 0x01000100u;
  uint4 r;
  r.x = __builtin_amdgcn_perm(thi, tlo, s0);
  r.y = __builtin_amdgcn_perm(thi, tlo, s1);
  r.z = __builtin_amdgcn_perm(thi, tlo, s2);
  r.w = __builtin_amdgcn_perm(thi, tlo, s3);
  return r;
}

// ---------------------------------------------------------------------------
// Kernel 2: grid (256,1), 512 threads. Wave w: wm=w>>1 (64 m-rows), tw=w&1
// (k-half of each 64-wide k-tile). Per body: prefetch A frags (global, ping-
// pong regs) + q2/norm (depth 2), 16 MFMA on current buffers, dequant next B
// tile into LDS[p^1], one barrier.
// ---------------------------------------------------------------------------
__global__ __launch_bounds__(512, 2) void gemm2bit_kernel(
    const uint4*    __restrict__ aws,  // A chunks (see cvt)
    const uint32_t* __restrict__ q2,   // [G][4] packed 2-bit (low byte crumbs)
    const float*    __restrict__ nrm,  // [G] group norms (f32)
    const float*    __restrict__ bias, // [N]
    float*          __restrict__ out)  // [256][16384] fp32
{
  __shared__ uint4 Bb[2][512];  // 8 chunks (ts*4+nb) x 64 slots, dbuf = 16 KiB
  __shared__ uint4 Sc[2048];    // epilogue k-split reduce scratch = 32 KiB

  const int tid  = threadIdx.x;
  const int lane = tid & 63;
  const int w    = tid >> 6;    // 0..7
  const int wm   = w >> 1;      // 0..3 : rows wm*64..+63
  const int tw   = w & 1;       // k-half of the 64-wide tile
  const int lo4  = lane & 15;
  const int qd   = lane >> 4;
  const int n0   = blockIdx.x * BN;

  // --- B staging role: one half-group (8 elems) per thread ---
  const int nloc = tid >> 3;          // 0..63 n-row within tile
  const int kg   = (tid >> 1) & 3;    // k-group (16 elems) within BK
  const int h    = tid & 1;           // which half of the group
  const int grow = n0 + nloc;
  // LDS slot: chunk cb = (kg>>1)*4 + (nloc>>4); within: qd' = (kg&1)*2+h
  const int bslot = ((kg >> 1) * 4 + (nloc >> 4)) * 64 + (kg & 1) * 32 + h * 16 + (nloc & 15);

  // --- pointers ---
  // A frag source: chunk (mb = wm*4+s, kch = 2t+tw), per-lane 16B slot
  const uint4* pA = aws + (((size_t)(wm * 4) * 128 + tw) * 64 + lane);
  // q2: group gidx = grow*256 + t*4 + kg; uint2 at gidx*4 + h*2
  const uint32_t* pq = q2 + ((size_t)grow * 256 + kg) * 4 + h * 2;
  const float*    pn = nrm + (size_t)grow * 256 + kg;

  f32x4 acc[4][4];
#pragma unroll
  for (int s = 0; s < 4; ++s)
#pragma unroll
    for (int u = 0; u < 4; ++u)
      acc[s][u] = (f32x4){0.f, 0.f, 0.f, 0.f};

  uint4 af0[4], af1[4];
  uint2 qA, qB;
  float nA, nB;

  // ---- prologue: tile0 A-frags + B dequant; tile1 q prefetched ----
#pragma unroll
  for (int s = 0; s < 4; ++s) af0[s] = pA[(size_t)s * 8192];
  uint2 q0 = *(const uint2*)pq;
  float n0v = pn[0];
  qA = *(const uint2*)(pq + 16);
  nA = pn[4];
  Bb[0][bslot] = deq8(q0, n0v);
  __syncthreads();

  // Body T: reads Bb[PR] + AFC (tile T); prefetches A(T+1)->AFN, q(T+2)->QN;
  // dequants tile T+1 (QC, loaded a body earlier) into Bb[PR^1]; one barrier.
#define GEMM_BODY(T, PR, AFC, AFN, QC, NC, QN, NN)                              \
  do {                                                                          \
    if ((T) + 1 < NT) {                                                         \
      size_t toff = (size_t)((T) + 1) * 128;                                    \
      _Pragma("unroll")                                                         \
      for (int s = 0; s < 4; ++s) AFN[s] = pA[(size_t)s * 8192 + toff];         \
    }                                                                           \
    if ((T) + 2 < NT) {                                                         \
      QN = *(const uint2*)(pq + (size_t)((T) + 2) * 16);                        \
      NN = pn[(size_t)((T) + 2) * 4];                                           \
    }                                                                           \
    bf16x8 bfv[4];                                                              \
    _Pragma("unroll")                                                           \
    for (int u = 0; u < 4; ++u)                                                 \
      bfv[u] = *(const bf16x8*)&Bb[PR][(tw * 4 + u) * 64 + lane];               \
    _Pragma("unroll")                                                           \
    for (int s = 0; s < 4; ++s) {                                               \
      bf16x8 av = __builtin_bit_cast(bf16x8, AFC[s]);                           \
      _Pragma("unroll")                                                         \
      for (int u = 0; u < 4; ++u)                                               \
        acc[s][u] = __builtin_amdgcn_mfma_f32_16x16x32_bf16(av, bfv[u],         \
                                                            acc[s][u], 0, 0, 0);\
    }                                                                           \
    if ((T) + 1 < NT) Bb[(PR) ^ 1][bslot] = deq8(QC, NC);                       \
    __syncthreads();                                                            \
  } while (0)

  for (int t2 = 0; t2 < NT; t2 += 2) {
    GEMM_BODY(t2,     0, af0, af1, qA, nA, qB, nB);
    GEMM_BODY(t2 + 1, 1, af1, af0, qB, nB, qA, nA);
  }
#undef GEMM_BODY

  // ---- epilogue: merge k-split partials (tw pairs) via LDS, add bias ----
  float bv[4];
#pragma unroll
  for (int u = 0; u < 4; ++u) bv[u] = bias[n0 + u * 16 + lo4];

  // phase 1: tw1 shares s=0,1; tw0 sums + stores rows s=0,1
  if (tw == 1) {
#pragma unroll
    for (int s = 0; s < 2; ++s)
#pragma unroll
      for (int u = 0; u < 4; ++u)
        Sc[((wm * 2 + s) * 4 + u) * 64 + lane] = __builtin_bit_cast(uint4, acc[s][u]);
  }
  __syncthreads();
  if (tw == 0) {
#pragma unroll
    for (int s = 0; s < 2; ++s)
#pragma unroll
      for (int u = 0; u < 4; ++u) {
        f32x4 o = acc[s][u] +
                  __builtin_bit_cast(f32x4, Sc[((wm * 2 + s) * 4 + u) * 64 + lane]);
        int mrow = wm * 64 + s * 16 + qd * 4;
        float* p = out + (size_t)mrow * N_DIM + (n0 + u * 16 + lo4);
#pragma unroll
        for (int r = 0; r < 4; ++r) p[(size_t)r * N_DIM] = o[r] + bv[u];
      }
  }
  __syncthreads();
  // phase 2: tw0 shares s=2,3; tw1 sums + stores rows s=2,3
  if (tw == 0) {
#pragma unroll
    for (int s = 2; s < 4; ++s)
#pragma unroll
      for (int u = 0; u < 4; ++u)
        Sc[((wm * 2 + (s - 2)) * 4 + u) * 64 + lane] = __builtin_bit_cast(uint4, acc[s][u]);
  }
  __syncthreads();
  if (tw == 1) {
#pragma unroll
    for (int s = 2; s < 4; ++s)
#pragma unroll
      for (int u = 0; u < 4; ++u) {
        f32x4 o = acc[s][u] +
                  __builtin_bit_cast(f32x4, Sc[((wm * 2 + (s - 2)) * 4 + u) * 64 + lane]);
        int mrow = wm * 64 + s * 16 + qd * 4;
        float* p = out + (size_t)mrow * N_DIM + (n0 + u * 16 + lo4);
#pragma unroll
        for (int r = 0; r < 4; ++r) p[(size_t)r * N_DIM] = o[r] + bv[u];
      }
  }
}

// ---------------------------------------------------------------------------
extern "C" void kernel_launch(void* const* d_in, const int* in_sizes, int n_in,
                              void* d_out, int out_size, void* d_ws, size_t ws_size,
                              hipStream_t stream) {
  const float*    x    = (const float*)d_in[0];
  const uint32_t* q2   = (const uint32_t*)d_in[1];
  const float*    nm   = (const float*)d_in[2];
  const float*    bias = (const float*)d_in[3];
  float*          out  = (float*)d_out;
  uint4*          aws  = (uint4*)d_ws;   // 2 MiB: x as bf16 fragment chunks

  cvt_x_kernel<<<512, 256, 0, stream>>>(x, aws);
  gemm2bit_kernel<<<dim3(N_DIM / BN, 1), 512, 0, stream>>>(aws, q2, nm, bias, out);
}

// Round 2
// 163.967 us; speedup vs baseline: 1.0893x; 1.0178x over previous
//
#include <hip/hip_runtime.h>
#include <stdint.h>

// Problem: out[m][n] = sum_k x[m][k] * w[n][k] + bias[n]
//   M=256, N=16384, K=4096, w = dequant(2-bit, group=16 along k)
// Round 2: BM=128, BN=64, BK=64, grid (256,2) = 512 blocks -> 2 blocks/CU so
// barrier stalls of one block are hidden by the other. 8 waves = 4(m) x 2(n),
// no k-split (no epilogue LDS merge). A is consumed directly from the
// fragment-ordered workspace (no LDS for A); only B goes through LDS (16KB
// double-buffered, XOR bank-swizzled to kill the 8-way ds_write conflict).
#define M_DIM 256
#define N_DIM 16384
#define K_DIM 4096
#define BN 64
#define BK 64
#define NT (K_DIM / BK)   // 64 k-tiles

typedef __bf16 bf16x8 __attribute__((ext_vector_type(8)));
typedef float  f32x4  __attribute__((ext_vector_type(4)));

// fp32 -> bf16 bits, round-nearest-even (finite inputs)
__device__ __forceinline__ uint32_t f2bf(float f) {
  uint32_t u = __float_as_uint(f);
  return (u + 0x7fffu + ((u >> 16) & 1u)) >> 16;
}

// ---------------------------------------------------------------------------
// Kernel 1 (unchanged): x fp32 [256][4096] -> bf16 fragment-chunk order.
// Chunk = (m-block of 16 rows) x (k-chunk of 32): 64 slots x 16B.
// Slot L holds row (L&15), k = (L>>4)*8 .. +7  (MFMA 16x16x32 A-frag order).
// ws uint4 index = (mb_glob*128 + kch)*64 + L.
// ---------------------------------------------------------------------------
__global__ __launch_bounds__(256) void cvt_x_kernel(const float* __restrict__ x,
                                                    uint4* __restrict__ ws) {
  int T = blockIdx.x * 256 + threadIdx.x;       // 0..131071
  int mb_glob = T >> 13;                        // 16 m-blocks
  int r       = T & 8191;
  int kch     = r >> 6;                         // 128 k-chunks
  int L       = r & 63;
  int row = mb_glob * 16 + (L & 15);
  int k   = kch * 32 + (L >> 4) * 8;
  const float* p = x + (size_t)row * K_DIM + k;
  float4 a = *(const float4*)p;
  float4 b = *(const float4*)(p + 4);
  uint4 o;
  o.x = f2bf(a.x) | (f2bf(a.y) << 16);
  o.y = f2bf(a.z) | (f2bf(a.w) << 16);
  o.z = f2bf(b.x) | (f2bf(b.y) << 16);
  o.w = f2bf(b.z) | (f2bf(b.w) << 16);
  ws[T] = o;
}

// ---------------------------------------------------------------------------
// Dequant 8 elems (2 packed q2 words; 4 crumbs in each low byte) of one group.
// Table entries {-n, a-n, 2a-n, 3a-n}, a = n*2/3 -- bit-identical to the
// fmaf+f2bf reference path.  v_perm_b32 picks the bf16 entry per crumb.
// ---------------------------------------------------------------------------
__device__ __forceinline__ uint4 deq8(uint2 q, float nv) {
  float a2 = nv * (2.0f / 3.0f);
  uint32_t tlo = f2bf(-nv) | (f2bf(fmaf(1.0f, a2, -nv)) << 16);
  uint32_t thi = f2bf(fmaf(2.0f, a2, -nv)) | (f2bf(fmaf(3.0f, a2, -nv)) << 16);
  uint32_t s0 = ((q.x & 3u) | ((q.x & 0xCu) << 14)) * 0x0202u + 0x01000100u;
  uint32_t s1 = (((q.x >> 4) & 3u) | ((q.x & 0xC0u) << 10)) * 0x0202u + 0x01000100u;
  uint32_t s2 = ((q.y & 3u) | ((q.y & 0xCu) << 14)) * 0x0202u + 0x01000100u;
  uint32_t s3 = (((q.y >> 4) & 3u) | ((q.y & 0xC0u) << 10)) * 0x0202u + 0x01000100u;
  uint4 r;
  r.x = __builtin_amdgcn_perm(thi, tlo, s0);
  r.y = __builtin_amdgcn_perm(thi, tlo, s1);
  r.z = __builtin_amdgcn_perm(thi, tlo, s2);
  r.w = __builtin_amdgcn_perm(thi, tlo, s3);
  return r;
}

// ---------------------------------------------------------------------------
// Kernel 2: grid (256,2), 512 threads. Wave w: wm=w>>1 (32 m-rows), wn=w&1
// (32 n-cols). Per body: prefetch A frags (global, ping-pong regs) + q2/norm
// (depth 2), 8 MFMA on current buffers, dequant next B tile into LDS[p^1],
// one barrier. B LDS slots XOR-swizzled: phys = logical ^ ((logical>>4)&3).
// ---------------------------------------------------------------------------
__global__ __launch_bounds__(512, 4) void gemm2bit_kernel(
    const uint4*    __restrict__ aws,  // A chunks (see cvt)
    const uint32_t* __restrict__ q2,   // [G][4] packed 2-bit (low byte crumbs)
    const float*    __restrict__ nrm,  // [G] group norms (f32)
    const float*    __restrict__ bias, // [N]
    float*          __restrict__ out)  // [256][16384] fp32
{
  __shared__ uint4 Bb[2][512];  // 8 chunks (ts*4+nb) x 64 slots, dbuf = 16 KiB

  const int tid  = threadIdx.x;
  const int lane = tid & 63;
  const int w    = tid >> 6;    // 0..7
  const int wm   = w >> 1;      // 0..3 : rows m0 + wm*32 .. +31
  const int wn   = w & 1;       // 0..1 : cols n0 + wn*32 .. +31
  const int lo4  = lane & 15;
  const int qd   = lane >> 4;
  const int n0   = blockIdx.x * BN;
  const int m0   = blockIdx.y * 128;

  // swizzled read lane: XOR qd into low 2 bits of lo4 (matches write swizzle)
  const int lrs = lane ^ qd;    // qd in 0..3, touches bits 0..1 only

  // --- B staging role: one half-group (8 elems) per thread ---
  const int nloc = tid >> 3;          // 0..63 n-row within tile
  const int kg   = (tid >> 1) & 3;    // k-group (16 elems) within BK
  const int h    = tid & 1;           // which half of the group
  const int grow = n0 + nloc;
  // logical slot: chunk cb = (kg>>1)*4 + (nloc>>4); within: qd2 = (kg&1)*2+h
  const int qd2   = (kg & 1) * 2 + h;
  const int bslot = ((kg >> 1) * 4 + (nloc >> 4)) * 64 + qd2 * 16 +
                    ((nloc & 15) ^ qd2);   // phys = logical ^ qd2

  // --- pointers ---
  // A frag source: chunk (mb = blockIdx.y*8 + wm*2 + s, kch = 2t + ts)
  const uint4* pA = aws + ((size_t)(blockIdx.y * 8 + wm * 2) * 128) * 64 + lane;
  // q2: group gidx = grow*256 + t*4 + kg; uint2 at gidx*4 + h*2
  const uint32_t* pq = q2 + ((size_t)grow * 256 + kg) * 4 + h * 2;
  const float*    pn = nrm + (size_t)grow * 256 + kg;

  f32x4 acc[2][2];
#pragma unroll
  for (int s = 0; s < 2; ++s)
#pragma unroll
    for (int u = 0; u < 2; ++u)
      acc[s][u] = (f32x4){0.f, 0.f, 0.f, 0.f};

  uint4 af0[4], af1[4];   // [s*2+ts]
  uint2 qA, qB;
  float nA, nB;

  // ---- prologue: tile0 A-frags + B dequant; tile1 q prefetched ----
#pragma unroll
  for (int s = 0; s < 2; ++s)
#pragma unroll
    for (int ts = 0; ts < 2; ++ts)
      af0[s * 2 + ts] = pA[(size_t)s * 8192 + ts * 64];
  uint2 q0 = *(const uint2*)pq;
  float n0v = pn[0];
  qA = *(const uint2*)(pq + 16);
  nA = pn[4];
  Bb[0][bslot] = deq8(q0, n0v);
  __syncthreads();

  // Body T: reads Bb[PR] + AFC (tile T); prefetches A(T+1)->AFN, q(T+2)->QN;
  // dequants tile T+1 (QC, loaded a body earlier) into Bb[PR^1]; one barrier.
#define GEMM_BODY(T, PR, AFC, AFN, QC, NC, QN, NN)                              \
  do {                                                                          \
    if ((T) + 1 < NT) {                                                         \
      size_t toff = (size_t)((T) + 1) * 128;                                    \
      _Pragma("unroll")                                                         \
      for (int s = 0; s < 2; ++s)                                               \
        _Pragma("unroll")                                                       \
        for (int ts = 0; ts < 2; ++ts)                                          \
          AFN[s * 2 + ts] = pA[(size_t)s * 8192 + toff + ts * 64];              \
    }                                                                           \
    if ((T) + 2 < NT) {                                                         \
      QN = *(const uint2*)(pq + (size_t)((T) + 2) * 16);                        \
      NN = pn[(size_t)((T) + 2) * 4];                                           \
    }                                                                           \
    _Pragma("unroll")                                                           \
    for (int ts = 0; ts < 2; ++ts) {                                            \
      bf16x8 bfv[2];                                                            \
      _Pragma("unroll")                                                         \
      for (int u = 0; u < 2; ++u)                                               \
        bfv[u] = *(const bf16x8*)&Bb[PR][(ts * 4 + wn * 2 + u) * 64 + lrs];     \
      _Pragma("unroll")                                                         \
      for (int s = 0; s < 2; ++s) {                                             \
        bf16x8 av = __builtin_bit_cast(bf16x8, AFC[s * 2 + ts]);                \
        _Pragma("unroll")                                                       \
        for (int u = 0; u < 2; ++u)                                             \
          acc[s][u] = __builtin_amdgcn_mfma_f32_16x16x32_bf16(av, bfv[u],       \
                                                              acc[s][u], 0, 0, 0);\
      }                                                                         \
    }                                                                           \
    if ((T) + 1 < NT) Bb[(PR) ^ 1][bslot] = deq8(QC, NC);                       \
    __syncthreads();                                                            \
  } while (0)

  for (int t2 = 0; t2 < NT; t2 += 2) {
    GEMM_BODY(t2,     0, af0, af1, qA, nA, qB, nB);
    GEMM_BODY(t2 + 1, 1, af1, af0, qB, nB, qA, nA);
  }
#undef GEMM_BODY

  // ---- epilogue: direct store (no k-split), C/D layout col=lane&15 (n),
  // row=(lane>>4)*4+reg (m) ----
  float bv[2];
#pragma unroll
  for (int u = 0; u < 2; ++u)
    bv[u] = bias[n0 + wn * 32 + u * 16 + lo4];

#pragma unroll
  for (int s = 0; s < 2; ++s) {
    int mrow = m0 + wm * 32 + s * 16 + qd * 4;
#pragma unroll
    for (int u = 0; u < 2; ++u) {
      int ncol = n0 + wn * 32 + u * 16 + lo4;
      float* p = out + (size_t)mrow * N_DIM + ncol;
#pragma unroll
      for (int r = 0; r < 4; ++r)
        p[(size_t)r * N_DIM] = acc[s][u][r] + bv[u];
    }
  }
}

// ---------------------------------------------------------------------------
extern "C" void kernel_launch(void* const* d_in, const int* in_sizes, int n_in,
                              void* d_out, int out_size, void* d_ws, size_t ws_size,
                              hipStream_t stream) {
  const float*    x    = (const float*)d_in[0];
  const uint32_t* q2   = (const uint32_t*)d_in[1];
  const float*    nm   = (const float*)d_in[2];
  const float*    bias = (const float*)d_in[3];
  float*          out  = (float*)d_out;
  uint4*          aws  = (uint4*)d_ws;   // 2 MiB: x as bf16 fragment chunks

  cvt_x_kernel<<<512, 256, 0, stream>>>(x, aws);
  gemm2bit_kernel<<<dim3(N_DIM / BN, 2), 512, 0, stream>>>(aws, q2, nm, bias, out);
}